// Round 5
// baseline (290.340 us; speedup 1.0000x reference)
//
#include <hip/hip_runtime.h>
#include <math.h>

constexpr int An = 3;
constexpr int Wd = 52;
constexpr int HWn = 2704;        // 52*52
constexpr int ATT = 85;
constexpr int CH = 208;          // 4 grid rows per decode tile
constexpr int PITCH = 209;       // odd -> bank stride 17, conflict-free both phases
constexpr int CHUNKS = 13;       // 2704 / 208
constexpr int DEC_BLOCKS = 96 * CHUNKS;    // 1248
constexpr int NC = An * HWn;     // 8112 candidates (batch 0)
constexpr int OUT_DEC = 32 * NC * ATT;     // 22064640 floats (decode output)
constexpr float NEGV = -1.0e9f;
constexpr int WS_SCORE_OFF = 65536;
constexpr int INFI = 0x7FFFFFFF;
constexpr size_t DEC_LDS = (size_t)ATT * PITCH * sizeof(float);   // 71,060 B

// NMS LDS float-offsets
constexpr int L_BX1  = 16384;    // keys u64[8192] occupy [0,16384)
constexpr int L_BY1  = 17408;
constexpr int L_BX2  = 18432;
constexpr int L_BY2  = 19456;
constexpr int L_BAR  = 20480;
constexpr int L_KEPT = 21504;    // float4[100]
constexpr int L_DET  = 21904;    // float[700]
constexpr int L_WMIN = 22604;    // int[32] (parity-double-buffered)
constexpr int L_META = 22636;    // int[4]
constexpr size_t NMS_LDS = 22640u * sizeof(float);                // 90,560 B

__device__ __forceinline__ float sig_precise(float x) {   // scoring path: keep expf
    return 1.0f / (1.0f + expf(-x));
}
__device__ __forceinline__ float sig_fast(float x) {      // decode path: loose tol
    return 1.0f / (1.0f + __expf(-x));
}

// ==================== kernel 1: prep (candidate scoring, batch 0) ====================
__global__ void __launch_bounds__(128)
yolo_prep(const float* __restrict__ in, const float* __restrict__ anc,
          float* __restrict__ ws)
{
    const int n = blockIdx.x * 128 + threadIdx.x;
    if (n >= NC) return;
    const int a   = n / HWn;
    const int pos = n - a * HWn;
    const float* p = in + (size_t)a * 85 * HWn + pos;

    const float tx = p[0];
    const float ty = p[HWn];
    const float tw = p[2 * HWn];
    const float th = p[3 * HWn];
    const float tc = p[4 * HWn];

    float m = -3.0e38f; int cp = 0;
    #pragma unroll
    for (int j0 = 0; j0 < 80; j0 += 16) {
        float v[16];
        #pragma unroll
        for (int u = 0; u < 16; ++u) v[u] = p[(size_t)(5 + j0 + u) * HWn];
        #pragma unroll
        for (int u = 0; u < 16; ++u) {
            if (v[u] > m) { m = v[u]; cp = j0 + u; }
        }
    }

    const float cc    = sig_precise(m);
    const float conf  = sig_precise(tc);
    const float score = __fmul_rn(conf, cc);
    const float aw = anc[(6 + a) * 2 + 0] * 0.125f;
    const float ah = anc[(6 + a) * 2 + 1] * 0.125f;
    const float cx = (sig_precise(tx) + (float)(pos % Wd)) / 52.0f;
    const float cy = (sig_precise(ty) + (float)(pos / Wd)) / 52.0f;
    const float bw = expf(tw) * aw / 52.0f;
    const float bh = expf(th) * ah / 52.0f;
    const float hw = __fmul_rn(bw, 0.5f);
    const float hh = __fmul_rn(bh, 0.5f);
    float4* w4 = (float4*)ws;
    w4[2 * n + 0] = make_float4(__fsub_rn(cx, hw), __fsub_rn(cy, hh),
                                __fadd_rn(cx, hw), __fadd_rn(cy, hh));
    w4[2 * n + 1] = make_float4(conf, cc, (float)cp, 0.0f);
    ws[WS_SCORE_OFF + n] = score;
}

// ==================== kernel 2: NMS (sort + 1-barrier-per-pick walk) ====================
__global__ void __launch_bounds__(1024)
yolo_nms(const float* __restrict__ ws, float* __restrict__ out)
{
    extern __shared__ float sm[];
    unsigned long long* keys = (unsigned long long*)sm;   // [8192]
    float* lx1 = sm + L_BX1;  float* ly1 = sm + L_BY1;
    float* lx2 = sm + L_BX2;  float* ly2 = sm + L_BY2;
    float* lar = sm + L_BAR;
    float4* keptv   = (float4*)(sm + L_KEPT);
    float* detstage = sm + L_DET;
    int*   wavemin  = (int*)(sm + L_WMIN);
    int*   meta     = (int*)(sm + L_META);
    const int tid  = threadIdx.x;
    const int lane = tid & 63;
    const int wv   = tid >> 6;

    if (tid == 0) meta[0] = 0;
    __syncthreads();

    // ---- compact valid candidates into packed keys (wave-aggregated) ----
    const float* wscore = ws + WS_SCORE_OFF;
    for (int k = 0; k < 8; ++k) {
        const int n = tid + k * 1024;
        const float s = (n < NC) ? wscore[n] : NEGV;
        const bool valid = (s >= 0.5f);
        const unsigned long long mask = __ballot(valid);
        if (mask != 0ULL) {
            const int leader = __ffsll((long long)mask) - 1;
            int base = 0;
            if (lane == leader) base = atomicAdd(&meta[0], __popcll(mask));
            base = __shfl(base, leader);
            if (valid) {
                const int slot = base + __popcll(mask & ((1ULL << lane) - 1ULL));
                keys[slot] =
                    ((unsigned long long)(0xFFFFFFFFu - __float_as_uint(s)) << 32)
                    | (unsigned)n;
            }
        }
    }
    __syncthreads();
    const int V = meta[0];
    int P2 = 1; while (P2 < V) P2 <<= 1;
    for (int i = V + tid; i < P2; i += 1024) keys[i] = ~0ULL;
    __syncthreads();

    // ---- bitonic ascending, pair-indexed: (score desc, index asc) ----
    for (int k = 2; k <= P2; k <<= 1) {
        for (int j = k >> 1; j > 0; j >>= 1) {
            for (int idx = tid; idx < (P2 >> 1); idx += 1024) {
                const int i = ((idx & ~(j - 1)) << 1) | (idx & (j - 1));
                const int l = i | j;
                const unsigned long long a = keys[i], b = keys[l];
                const bool up = ((i & k) == 0);
                if (up ? (b < a) : (a < b)) { keys[i] = b; keys[l] = a; }
            }
            __syncthreads();
        }
    }

    // ---- greedy walk: super-batches of 1024, ONE barrier per pick ----
    const float4* w4 = (const float4*)ws;
    int nk = 0;
    for (int base = 0; base < V && nk < 100; base += 1024) {
        const int cidx = base + tid;
        bool alive = (cidx < V);
        float rx1 = 0, ry1 = 0, rx2 = 0, ry2 = 0, mconf = 0, mcc = 0, mcp = 0;
        float ox1 = 0, oy1 = 0, ox2 = 0, oy2 = 0, aC = 0;
        if (alive) {
            const int n = (int)(keys[cidx] & 0xFFFFFFFFu);
            const float4 bx = w4[2 * n], mt = w4[2 * n + 1];
            rx1 = bx.x; ry1 = bx.y; rx2 = bx.z; ry2 = bx.w;
            mconf = mt.x; mcc = mt.y; mcp = mt.z;
            const float off = __fmul_rn(mcp, 4096.0f);
            ox1 = __fadd_rn(rx1, off); oy1 = __fadd_rn(ry1, off);
            ox2 = __fadd_rn(rx2, off); oy2 = __fadd_rn(ry2, off);
            aC  = __fmul_rn(__fsub_rn(ox2, ox1), __fsub_rn(oy2, oy1));
            lx1[tid] = ox1; ly1[tid] = oy1; lx2[tid] = ox2; ly2[tid] = oy2;
            lar[tid] = aC;
            // snapshot vs all kept so far (16-wave parallel)
            for (int t = 0; t < nk && alive; ++t) {
                const float4 kb = keptv[t];
                const float ltx = fmaxf(kb.x, ox1), lty = fmaxf(kb.y, oy1);
                const float rbx = fminf(kb.z, ox2), rby = fminf(kb.w, oy2);
                const float iw = fmaxf(__fsub_rn(rbx, ltx), 0.0f);
                const float ih = fmaxf(__fsub_rn(rby, lty), 0.0f);
                const float inter = __fmul_rn(iw, ih);
                const float aK = __fmul_rn(__fsub_rn(kb.z, kb.x), __fsub_rn(kb.w, kb.y));
                const float den = __fadd_rn(__fsub_rn(__fadd_rn(aK, aC), inter), 1e-9f);
                if (inter / den > 0.4f) alive = false;
            }
        }

        int it = 0;
        while (true) {
            const unsigned long long mb = __ballot(alive);
            if (lane == 0)
                wavemin[(it & 1) * 16 + wv] =
                    mb ? (wv * 64 + (__ffsll((long long)mb) - 1)) : INFI;
            __syncthreads();   // also makes staging (it==0) visible
            int win = INFI;
            #pragma unroll
            for (int w = 0; w < 16; ++w)
                win = min(win, wavemin[(it & 1) * 16 + w]);
            if (win == INFI) break;                      // batch exhausted (uniform)
            if (tid == win) {
                keptv[nk] = make_float4(ox1, oy1, ox2, oy2);
                float* dr = detstage + nk * 7;
                const float xm  = __fmul_rn(__fadd_rn(rx1, rx2), 0.5f);
                const float ym  = __fmul_rn(__fadd_rn(ry1, ry2), 0.5f);
                const float hw2 = __fmul_rn(__fsub_rn(rx2, rx1), 0.5f);
                const float hh2 = __fmul_rn(__fsub_rn(ry2, ry1), 0.5f);
                dr[0] = __fmul_rn(__fsub_rn(ym, hh2), 416.0f);
                dr[1] = __fmul_rn(__fsub_rn(xm, hw2), 416.0f);
                dr[2] = __fmul_rn(__fadd_rn(ym, hh2), 416.0f);
                dr[3] = __fmul_rn(__fadd_rn(xm, hw2), 416.0f);
                dr[4] = mconf; dr[5] = mcc; dr[6] = mcp;
                alive = false;
            }
            ++nk;
            if (nk == 100) break;                        // uniform
            if (alive) {   // test vs winner, read DIRECTLY from LDS by index
                const float wx1 = lx1[win], wy1 = ly1[win];
                const float wx2 = lx2[win], wy2 = ly2[win], aW = lar[win];
                const float ltx = fmaxf(wx1, ox1), lty = fmaxf(wy1, oy1);
                const float rbx = fminf(wx2, ox2), rby = fminf(wy2, oy2);
                const float iw = fmaxf(__fsub_rn(rbx, ltx), 0.0f);
                const float ih = fmaxf(__fsub_rn(rby, lty), 0.0f);
                const float inter = __fmul_rn(iw, ih);
                const float den = __fadd_rn(__fsub_rn(__fadd_rn(aW, aC), inter), 1e-9f);
                if (inter / den > 0.4f) alive = false;
            }
            ++it;
        }
        __syncthreads();   // keptv/detstage visible; safe to restage lx* next batch
    }

    // ---- write det (nk is uniform): staged rows, zeros for rows >= nk ----
    for (int i = tid; i < 100 * 7; i += 1024) {
        out[OUT_DEC + i] = (i < nk * 7) ? detstage[i] : 0.0f;
    }
}

// ==================== kernel 3: decode (proven conflict-free layout) ====================
__global__ void __launch_bounds__(1024)
yolo_decode(const float* __restrict__ in, const float* __restrict__ anc,
            float* __restrict__ out)
{
    extern __shared__ float smem[];
    const int tid = threadIdx.x;
    const int bi    = (int)blockIdx.x;
    const int chunk = bi % CHUNKS;
    const int ba    = bi / CHUNKS;
    const int a     = ba % An;
    const float anc_w = anc[(6 + a) * 2 + 0] * 0.125f;
    const float anc_h = anc[(6 + a) * 2 + 1] * 0.125f;
    const int pos0  = chunk * CH;
    const float* src = in + (size_t)ba * 85 * HWn + pos0;

    // load+transform: coalesced global, stride-1 LDS writes (conflict-free)
    for (int i = tid; i < ATT * CH; i += 1024) {
        const int attr = i / CH;
        const int p    = i - attr * CH;
        const int pos  = pos0 + p;
        const float x  = src[(size_t)attr * HWn + p];
        float v;
        if (attr >= 4)      v = sig_fast(x);
        else if (attr == 0) v = (sig_fast(x) + (float)(pos % Wd)) / 52.0f;
        else if (attr == 1) v = (sig_fast(x) + (float)(pos / Wd)) / 52.0f;
        else if (attr == 2) v = __expf(x) * anc_w / 52.0f;
        else                v = __expf(x) * anc_h / 52.0f;
        smem[attr * PITCH + p] = v;
    }
    __syncthreads();

    // store: contiguous global, LDS stride 209 (bank step 17, conflict-free)
    float* dst = out + ((size_t)ba * HWn + pos0) * ATT;
    for (int f = tid; f < CH * ATT; f += 1024) {
        const int p    = f / ATT;
        const int attr = f - p * ATT;
        dst[f] = smem[attr * PITCH + p];
    }
}

extern "C" void kernel_launch(void* const* d_in, const int* in_sizes, int n_in,
                              void* d_out, int out_size, void* d_ws, size_t ws_size,
                              hipStream_t stream) {
    const float* in  = (const float*)d_in[0];
    const float* anc = (const float*)d_in[1];
    float* out = (float*)d_out;
    float* ws  = (float*)d_ws;

    hipLaunchKernelGGL(yolo_prep, dim3((NC + 127) / 128), dim3(128), 0, stream,
                       in, anc, ws);
    hipLaunchKernelGGL(yolo_nms, dim3(1), dim3(1024), NMS_LDS, stream, ws, out);
    hipLaunchKernelGGL(yolo_decode, dim3(DEC_BLOCKS), dim3(1024), DEC_LDS, stream,
                       in, anc, out);
}